// Round 2
// baseline (189.559 us; speedup 1.0000x reference)
//
#include <hip/hip_runtime.h>
#include <hip/hip_bf16.h>

// out[b,o,n] = sum_{k<19,c<64} x[b,c,neigh[n,k]] * W[o,k*64+c] + bias[o]
// B=4, N_VERTS=40962, K_RING=19, C=64. Storage: x,W,b,out fp32 (values
// bf16-representable), neigh int32. bf16 MFMA path near-exact (1.6e-2).
//
// R11: R10 (barrier-free, fragment-W from global) was right to drop the
// per-ring-pair vmcnt(0) barrier drains, but wrong to halve the grid:
// occupancy fell 34.7->23.2% and the kernel is LATENCY-bound on random
// 128B gathers, so wave count is the hiding resource. R11 restores
// 32 verts/wave (grid 1288, 5 blocks/CU) and deepens the pipeline:
// x-gathers prefetched 2 rings ahead, neigh indices 3 ahead, W loaded
// per-ring (L1/L2-hot) in kc-halves to cap live VGPRs. Coverage per wave
// = 2 rings x 78 cyc x 4 waves/SIMD >> gather latency.

#define NV   40962
#define KR   19
#define CIN  64
#define COUT 64
#define NB   4
#define NTILES 321   // ceil(NV/128), 128 verts per block (32 per wave)

typedef __bf16 bf16;
typedef __bf16 bf16x8 __attribute__((ext_vector_type(8)));
typedef float  floatx4 __attribute__((ext_vector_type(4)));

#define XT_ELEMS ((size_t)NB * NV * CIN)
#define WB_OFF   ((XT_ELEMS * 2 + 255) & ~(size_t)255)
#define WS_NEED  (WB_OFF + (size_t)COUT * KR * CIN * 2)

// ---------------------------------------------------------------------------
// Kernel 1: x (B,C,N) fp32 -> xt (B,N,64) bf16 (row per vertex = 128B line).
// ---------------------------------------------------------------------------
__global__ __launch_bounds__(256) void transpose_kernel(
    const float* __restrict__ x, bf16* __restrict__ xt)
{
    __shared__ float tile[64 * 65];
    const int b  = blockIdx.y;
    const int v0 = blockIdx.x * 64;
    const int t  = threadIdx.x;

    const int vl = t & 63;
    const int c0 = t >> 6;
    const int vg = min(v0 + vl, NV - 1);
    #pragma unroll
    for (int p = 0; p < 16; ++p) {
        int c = c0 * 16 + p;
        tile[vl * 65 + c] = x[((size_t)(b * CIN + c)) * NV + vg];
    }
    __syncthreads();

    const int v = t >> 2;
    const int q = t & 3;
    if (v0 + v < NV) {
        #pragma unroll
        for (int p = 0; p < 2; ++p) {
            int chunk = q + p * 4;
            bf16x8 o;
            #pragma unroll
            for (int j = 0; j < 8; ++j)
                o[j] = (bf16)tile[v * 65 + chunk * 8 + j];
            *(bf16x8*)&xt[((size_t)(b * NV + v0 + v)) * 64 + chunk * 8] = o;
        }
    }
}

// ---------------------------------------------------------------------------
// Kernel 1b: W fp32 (64x1216) -> bf16 in MFMA A-fragment layout (152 KB).
// Fragment id = ring*8 + ot*2 + kc. Within a fragment, lane L (=g*16+l15)
// holds 8 contiguous bf16:
//   Wf[(frag*64 + L)*8 + j] = W[ot*16 + l15][ring*64 + kc*32 + g*8 + j]
// ---------------------------------------------------------------------------
__global__ __launch_bounds__(256) void convw_kernel(
    const float* __restrict__ W, bf16* __restrict__ Wf)
{
    const int idx = blockIdx.x * 256 + threadIdx.x;   // (ring, f, lane)
    if (idx >= KR * 8 * 64) return;
    const int lane = idx & 63;
    const int f    = (idx >> 6) & 7;
    const int ring = idx >> 9;
    const int ot   = f >> 1;
    const int kc   = f & 1;
    const int row  = ot * 16 + (lane & 15);
    const int col0 = ring * 64 + kc * 32 + (lane >> 4) * 8;
    const float* src = W + (size_t)row * (KR * CIN) + col0;
    float4 a = *(const float4*)(src);
    float4 c = *(const float4*)(src + 4);
    bf16x8 o;
    o[0] = (bf16)a.x; o[1] = (bf16)a.y; o[2] = (bf16)a.z; o[3] = (bf16)a.w;
    o[4] = (bf16)c.x; o[5] = (bf16)c.y; o[6] = (bf16)c.z; o[7] = (bf16)c.w;
    *(bf16x8*)(Wf + (size_t)idx * 8) = o;
}

// ---------------------------------------------------------------------------
// Kernel 2: gather-GEMM, mfma_f32_16x16x32_bf16. Barrier-free, LDS-free.
// Per wave: 32 vertices (2 s-tiles) x 64 outputs. Per ring: 2 neigh dwords
// (prefetched 3 ahead), 4 gather b128 (prefetched 2 ahead), 8 W b128
// (same-ring, L1/L2-hot, kc-split to cap live regs), 16 MFMAs.
// ---------------------------------------------------------------------------
__global__ __launch_bounds__(256, 4) void conv_kernel(
    const int*   __restrict__ neigh,
    const bf16*  __restrict__ xt,
    const bf16*  __restrict__ Wf,     // fragment layout, 19*8*64*8 bf16
    const float* __restrict__ bias,   // (64,) fp32
    float*       __restrict__ out)    // (B, 64, NV) fp32
{
    const int i    = blockIdx.x;
    const int b    = (i & 7) >> 1;                  // XCD pair -> batch
    const int tile = (i >> 3) * 2 + (i & 1);
    if (tile >= NTILES) return;

    const int t    = threadIdx.x;
    const int wv   = t >> 6;
    const int lane = t & 63;
    const int l15  = lane & 15;
    const int g    = lane >> 4;

    const int n0 = tile * 128 + wv * 32;

    int nn[2], ib[2];
    #pragma unroll
    for (int s = 0; s < 2; ++s) {
        nn[s] = n0 + s * 16 + l15;
        ib[s] = min(nn[s], NV - 1) * KR;
    }

    const bf16* xb = xt + (((size_t)b * NV) << 6) + g * 8;   // + (v<<6)
    const bf16* wb = Wf + lane * 8;                          // + ring*4096 + f*512

    floatx4 acc[2][4];
    #pragma unroll
    for (int s = 0; s < 2; ++s)
        #pragma unroll
        for (int o = 0; o < 4; ++o)
            acc[s][o] = (floatx4){0.f, 0.f, 0.f, 0.f};

    // ---- prologue: indices for rings 0,1,2; gathers for rings 0,1
    int i0[2], i1[2], vic[2];
    #pragma unroll
    for (int s = 0; s < 2; ++s) {
        i0[s]  = neigh[ib[s] + 0];
        i1[s]  = neigh[ib[s] + 1];
        vic[s] = neigh[ib[s] + 2];
    }
    bf16x8 xf[2][2], xg[2][2];
    #pragma unroll
    for (int s = 0; s < 2; ++s) {
        int v = ((unsigned)i0[s] < (unsigned)NV) ? i0[s] : 0;
        const bf16* p = xb + ((size_t)v << 6);
        xf[s][0] = *(const bf16x8*)(p);
        xf[s][1] = *(const bf16x8*)(p + 32);
        v = ((unsigned)i1[s] < (unsigned)NV) ? i1[s] : 0;
        p = xb + ((size_t)v << 6);
        xg[s][0] = *(const bf16x8*)(p);
        xg[s][1] = *(const bf16x8*)(p + 32);
    }

    #pragma unroll
    for (int r = 0; r < KR; ++r) {
        // prefetch: indices ring r+3, gathers ring r+2
        int vid[2];
        if (r + 3 < KR) {
            #pragma unroll
            for (int s = 0; s < 2; ++s)
                vid[s] = neigh[ib[s] + r + 3];
        }
        bf16x8 xh[2][2];
        if (r + 2 < KR) {
            #pragma unroll
            for (int s = 0; s < 2; ++s) {
                int v = ((unsigned)vic[s] < (unsigned)NV) ? vic[s] : 0;
                const bf16* p = xb + ((size_t)v << 6);
                xh[s][0] = *(const bf16x8*)(p);
                xh[s][1] = *(const bf16x8*)(p + 32);
            }
        }

        // ---- compute ring r (W loaded here, L1/L2-hot; kc-split)
        const bf16* wr = wb + (size_t)r * 4096;
        #pragma unroll
        for (int kc = 0; kc < 2; ++kc) {
            bf16x8 wf[4];
            #pragma unroll
            for (int ot = 0; ot < 4; ++ot)
                wf[ot] = *(const bf16x8*)(wr + (ot * 2 + kc) * 512);
            #pragma unroll
            for (int ot = 0; ot < 4; ++ot)
                #pragma unroll
                for (int s = 0; s < 2; ++s)
                    acc[s][ot] = __builtin_amdgcn_mfma_f32_16x16x32_bf16(
                        wf[ot], xf[s][kc], acc[s][ot], 0, 0, 0);
        }

        // ---- rotate pipeline (SSA-renamed under full unroll)
        if (r + 1 < KR) {
            #pragma unroll
            for (int s = 0; s < 2; ++s) {
                xf[s][0] = xg[s][0];
                xf[s][1] = xg[s][1];
            }
        }
        if (r + 2 < KR) {
            #pragma unroll
            for (int s = 0; s < 2; ++s) {
                xg[s][0] = xh[s][0];
                xg[s][1] = xh[s][1];
            }
        }
        if (r + 3 < KR) {
            #pragma unroll
            for (int s = 0; s < 2; ++s)
                vic[s] = vid[s];
        }
    }

    // ---- epilogue: C/D layout col=l15 (vertex), row=g*4+ii (output)
    #pragma unroll
    for (int ot = 0; ot < 4; ++ot) {
        #pragma unroll
        for (int ii = 0; ii < 4; ++ii) {
            const int o = ot * 16 + g * 4 + ii;
            const float bv = bias[o];
            #pragma unroll
            for (int s = 0; s < 2; ++s) {
                if (nn[s] < NV) {
                    out[((size_t)(b * COUT + o)) * NV + nn[s]] =
                        acc[s][ot][ii] + bv;
                }
            }
        }
    }
}

// ---------------------------------------------------------------------------
// Fallback (no workspace): one block per (b,n); fp32 in/out.
// ---------------------------------------------------------------------------
__global__ __launch_bounds__(64) void fallback_kernel(
    const int*   __restrict__ neigh,
    const float* __restrict__ x,
    const float* __restrict__ W,
    const float* __restrict__ bias,
    float*       __restrict__ out)
{
    __shared__ float xg[KR * CIN];
    const int bn = blockIdx.x;
    const int b  = bn / NV;
    const int n  = bn % NV;
    const int t  = threadIdx.x;

    for (int k = t; k < KR * CIN; k += 64) {
        int r = k / CIN, c = k - r * CIN;
        int v = neigh[n * KR + r];
        v = ((unsigned)v < (unsigned)NV) ? v : 0;
        xg[k] = x[((size_t)(b * CIN + c)) * NV + v];
    }
    __syncthreads();

    float s = bias[t];
    const float* wrow = W + (size_t)t * (KR * CIN);
    for (int k = 0; k < KR * CIN; ++k) s += xg[k] * wrow[k];
    out[((size_t)(b * COUT + t)) * NV + n] = s;
}

// ---------------------------------------------------------------------------
extern "C" void kernel_launch(void* const* d_in, const int* in_sizes, int n_in,
                              void* d_out, int out_size, void* d_ws, size_t ws_size,
                              hipStream_t stream)
{
    const float* x     = (const float*)d_in[0];
    const int*   neigh = (const int*)d_in[1];
    const float* W     = (const float*)d_in[2];
    const float* bias  = (const float*)d_in[3];
    float* out = (float*)d_out;

    if (d_ws != nullptr && ws_size >= WS_NEED) {
        bf16* xt = (bf16*)d_ws;
        bf16* Wf = (bf16*)((char*)d_ws + WB_OFF);

        dim3 tgrid((NV + 63) / 64, NB);
        transpose_kernel<<<tgrid, 256, 0, stream>>>(x, xt);
        convw_kernel<<<(KR * 8 * 64 + 255) / 256, 256, 0, stream>>>(W, Wf);

        int nblk = 8 * ((NTILES + 1) / 2);          // 1288
        conv_kernel<<<nblk, 256, 0, stream>>>(neigh, xt, Wf, bias, out);
    } else {
        fallback_kernel<<<NB * NV, 64, 0, stream>>>(neigh, x, W, bias, out);
    }
}

// Round 3
// 179.519 us; speedup vs baseline: 1.0559x; 1.0559x over previous
//
#include <hip/hip_runtime.h>
#include <hip/hip_bf16.h>

// out[b,o,n] = sum_{k<19,c<64} x[b,c,neigh[n,k]] * W[o,k*64+c] + bias[o]
// B=4, N_VERTS=40962, K_RING=19, C=64. Storage: x,W,b,out fp32 (values
// bf16-representable), neigh int32. bf16 MFMA path near-exact (1.6e-2).
//
// R12: fix R11's two pipeline-killers.
//  (1) __launch_bounds__(256,4) capped arch-VGPRs at 64, so the compiler
//      sank all "prefetches" next to their uses (VGPR_Count=56 proved it)
//      -> effective depth-0 pipeline. Now (256,3): ~168-reg budget.
//  (2) W was loaded and consumed in the SAME ring: vmcnt is in-order, so
//      waiting on the newest load drains ALL in-flight gathers (rebuilt
//      R9's barrier-drain 19x per block). Now W is prefetched one ring
//      ahead like x; every consume is a counted vmcnt(12..20), never 0.
// s_setprio(1) wraps the MFMA cluster (barrier-free waves are
// phase-diverse -> scheduler has something to arbitrate).

#define NV   40962
#define KR   19
#define CIN  64
#define COUT 64
#define NB   4
#define NTILES 321   // ceil(NV/128), 128 verts per block (32 per wave)

typedef __bf16 bf16;
typedef __bf16 bf16x8 __attribute__((ext_vector_type(8)));
typedef float  floatx4 __attribute__((ext_vector_type(4)));

#define XT_ELEMS ((size_t)NB * NV * CIN)
#define WB_OFF   ((XT_ELEMS * 2 + 255) & ~(size_t)255)
#define WS_NEED  (WB_OFF + (size_t)COUT * KR * CIN * 2)

// ---------------------------------------------------------------------------
// Kernel 1: x (B,C,N) fp32 -> xt (B,N,64) bf16 (row per vertex = 128B line).
// ---------------------------------------------------------------------------
__global__ __launch_bounds__(256) void transpose_kernel(
    const float* __restrict__ x, bf16* __restrict__ xt)
{
    __shared__ float tile[64 * 65];
    const int b  = blockIdx.y;
    const int v0 = blockIdx.x * 64;
    const int t  = threadIdx.x;

    const int vl = t & 63;
    const int c0 = t >> 6;
    const int vg = min(v0 + vl, NV - 1);
    #pragma unroll
    for (int p = 0; p < 16; ++p) {
        int c = c0 * 16 + p;
        tile[vl * 65 + c] = x[((size_t)(b * CIN + c)) * NV + vg];
    }
    __syncthreads();

    const int v = t >> 2;
    const int q = t & 3;
    if (v0 + v < NV) {
        #pragma unroll
        for (int p = 0; p < 2; ++p) {
            int chunk = q + p * 4;
            bf16x8 o;
            #pragma unroll
            for (int j = 0; j < 8; ++j)
                o[j] = (bf16)tile[v * 65 + chunk * 8 + j];
            *(bf16x8*)&xt[((size_t)(b * NV + v0 + v)) * 64 + chunk * 8] = o;
        }
    }
}

// ---------------------------------------------------------------------------
// Kernel 1b: W fp32 (64x1216) -> bf16 in MFMA A-fragment layout (152 KB).
// Fragment id = ring*8 + ot*2 + kc. Within a fragment, lane L (=g*16+l15)
// holds 8 contiguous bf16:
//   Wf[(frag*64 + L)*8 + j] = W[ot*16 + l15][ring*64 + kc*32 + g*8 + j]
// ---------------------------------------------------------------------------
__global__ __launch_bounds__(256) void convw_kernel(
    const float* __restrict__ W, bf16* __restrict__ Wf)
{
    const int idx = blockIdx.x * 256 + threadIdx.x;   // (ring, f, lane)
    if (idx >= KR * 8 * 64) return;
    const int lane = idx & 63;
    const int f    = (idx >> 6) & 7;
    const int ring = idx >> 9;
    const int ot   = f >> 1;
    const int kc   = f & 1;
    const int row  = ot * 16 + (lane & 15);
    const int col0 = ring * 64 + kc * 32 + (lane >> 4) * 8;
    const float* src = W + (size_t)row * (KR * CIN) + col0;
    float4 a = *(const float4*)(src);
    float4 c = *(const float4*)(src + 4);
    bf16x8 o;
    o[0] = (bf16)a.x; o[1] = (bf16)a.y; o[2] = (bf16)a.z; o[3] = (bf16)a.w;
    o[4] = (bf16)c.x; o[5] = (bf16)c.y; o[6] = (bf16)c.z; o[7] = (bf16)c.w;
    *(bf16x8*)(Wf + (size_t)idx * 8) = o;
}

// ---------------------------------------------------------------------------
// Kernel 2: gather-GEMM, mfma_f32_16x16x32_bf16. Barrier-free, LDS-free.
// Per wave: 32 vertices (2 s-tiles) x 64 outputs. Per ring iteration,
// issue order (kept so every consume is a COUNTED vmcnt):
//   neigh idx ring r+2  (2 dword)
//   x gathers ring r+1  (4 b128, random 128B rows, L2/L3-hot)
//   W frags  ring r+1   (8 b128, L1/L2-hot, coalesced 1KB each)
//   MFMA ring r         (16 mfma, consumes loads issued LAST iteration)
// ---------------------------------------------------------------------------
__global__ __launch_bounds__(256, 3) void conv_kernel(
    const int*   __restrict__ neigh,
    const bf16*  __restrict__ xt,
    const bf16*  __restrict__ Wf,     // fragment layout, 19*8*64*8 bf16
    const float* __restrict__ bias,   // (64,) fp32
    float*       __restrict__ out)    // (B, 64, NV) fp32
{
    const int i    = blockIdx.x;
    const int b    = (i & 7) >> 1;                  // XCD pair -> batch
    const int tile = (i >> 3) * 2 + (i & 1);
    if (tile >= NTILES) return;

    const int t    = threadIdx.x;
    const int wv   = t >> 6;
    const int lane = t & 63;
    const int l15  = lane & 15;
    const int g    = lane >> 4;

    const int n0 = tile * 128 + wv * 32;

    int nn[2], ib[2];
    #pragma unroll
    for (int s = 0; s < 2; ++s) {
        nn[s] = n0 + s * 16 + l15;
        ib[s] = min(nn[s], NV - 1) * KR;
    }

    const bf16* xb = xt + (((size_t)b * NV) << 6) + g * 8;   // + (v<<6)
    const bf16* wb = Wf + lane * 8;                          // + ring*4096 + f*512

    floatx4 acc[2][4];
    #pragma unroll
    for (int s = 0; s < 2; ++s)
        #pragma unroll
        for (int o = 0; o < 4; ++o)
            acc[s][o] = (floatx4){0.f, 0.f, 0.f, 0.f};

    // ---- prologue: idx rings 0,1; gathers+W ring 0
    int icur[2], inxt[2];
    #pragma unroll
    for (int s = 0; s < 2; ++s) {
        icur[s] = neigh[ib[s] + 0];
        inxt[s] = neigh[ib[s] + 1];
    }
    bf16x8 xf[2][2], wf[8];
    #pragma unroll
    for (int s = 0; s < 2; ++s) {
        int v = ((unsigned)icur[s] < (unsigned)NV) ? icur[s] : 0;
        const bf16* p = xb + ((size_t)v << 6);
        xf[s][0] = *(const bf16x8*)(p);
        xf[s][1] = *(const bf16x8*)(p + 32);
    }
    #pragma unroll
    for (int f = 0; f < 8; ++f)
        wf[f] = *(const bf16x8*)(wb + f * 512);

    #pragma unroll
    for (int r = 0; r < KR; ++r) {
        int i2[2];
        bf16x8 xg[2][2], wg[8];

        // ---- issue ring r+2 indices
        if (r + 2 < KR) {
            #pragma unroll
            for (int s = 0; s < 2; ++s)
                i2[s] = neigh[ib[s] + r + 2];
        }
        // ---- issue ring r+1 gathers + W frags
        if (r + 1 < KR) {
            #pragma unroll
            for (int s = 0; s < 2; ++s) {
                int v = ((unsigned)inxt[s] < (unsigned)NV) ? inxt[s] : 0;
                const bf16* p = xb + ((size_t)v << 6);
                xg[s][0] = *(const bf16x8*)(p);
                xg[s][1] = *(const bf16x8*)(p + 32);
            }
            const bf16* wr = wb + (size_t)(r + 1) * 4096;
            #pragma unroll
            for (int f = 0; f < 8; ++f)
                wg[f] = *(const bf16x8*)(wr + f * 512);
        }

        // ---- compute ring r (consumes loads issued one iteration ago)
        __builtin_amdgcn_s_setprio(1);
        #pragma unroll
        for (int kc = 0; kc < 2; ++kc)
            #pragma unroll
            for (int ot = 0; ot < 4; ++ot)
                #pragma unroll
                for (int s = 0; s < 2; ++s)
                    acc[s][ot] = __builtin_amdgcn_mfma_f32_16x16x32_bf16(
                        wf[ot * 2 + kc], xf[s][kc], acc[s][ot], 0, 0, 0);
        __builtin_amdgcn_s_setprio(0);

        // ---- rotate (SSA-renamed under full unroll)
        if (r + 1 < KR) {
            #pragma unroll
            for (int s = 0; s < 2; ++s) {
                xf[s][0] = xg[s][0];
                xf[s][1] = xg[s][1];
                icur[s]  = inxt[s];
            }
            #pragma unroll
            for (int f = 0; f < 8; ++f)
                wf[f] = wg[f];
        }
        if (r + 2 < KR) {
            #pragma unroll
            for (int s = 0; s < 2; ++s)
                inxt[s] = i2[s];
        }
    }

    // ---- epilogue: C/D layout col=l15 (vertex), row=g*4+ii (output)
    #pragma unroll
    for (int ot = 0; ot < 4; ++ot) {
        #pragma unroll
        for (int ii = 0; ii < 4; ++ii) {
            const int o = ot * 16 + g * 4 + ii;
            const float bv = bias[o];
            #pragma unroll
            for (int s = 0; s < 2; ++s) {
                if (nn[s] < NV) {
                    out[((size_t)(b * COUT + o)) * NV + nn[s]] =
                        acc[s][ot][ii] + bv;
                }
            }
        }
    }
}

// ---------------------------------------------------------------------------
// Fallback (no workspace): one block per (b,n); fp32 in/out.
// ---------------------------------------------------------------------------
__global__ __launch_bounds__(64) void fallback_kernel(
    const int*   __restrict__ neigh,
    const float* __restrict__ x,
    const float* __restrict__ W,
    const float* __restrict__ bias,
    float*       __restrict__ out)
{
    __shared__ float xg[KR * CIN];
    const int bn = blockIdx.x;
    const int b  = bn / NV;
    const int n  = bn % NV;
    const int t  = threadIdx.x;

    for (int k = t; k < KR * CIN; k += 64) {
        int r = k / CIN, c = k - r * CIN;
        int v = neigh[n * KR + r];
        v = ((unsigned)v < (unsigned)NV) ? v : 0;
        xg[k] = x[((size_t)(b * CIN + c)) * NV + v];
    }
    __syncthreads();

    float s = bias[t];
    const float* wrow = W + (size_t)t * (KR * CIN);
    for (int k = 0; k < KR * CIN; ++k) s += xg[k] * wrow[k];
    out[((size_t)(b * COUT + t)) * NV + n] = s;
}

// ---------------------------------------------------------------------------
extern "C" void kernel_launch(void* const* d_in, const int* in_sizes, int n_in,
                              void* d_out, int out_size, void* d_ws, size_t ws_size,
                              hipStream_t stream)
{
    const float* x     = (const float*)d_in[0];
    const int*   neigh = (const int*)d_in[1];
    const float* W     = (const float*)d_in[2];
    const float* bias  = (const float*)d_in[3];
    float* out = (float*)d_out;

    if (d_ws != nullptr && ws_size >= WS_NEED) {
        bf16* xt = (bf16*)d_ws;
        bf16* Wf = (bf16*)((char*)d_ws + WB_OFF);

        dim3 tgrid((NV + 63) / 64, NB);
        transpose_kernel<<<tgrid, 256, 0, stream>>>(x, xt);
        convw_kernel<<<(KR * 8 * 64 + 255) / 256, 256, 0, stream>>>(W, Wf);

        int nblk = 8 * ((NTILES + 1) / 2);          // 1288
        conv_kernel<<<nblk, 256, 0, stream>>>(neigh, xt, Wf, bias, out);
    } else {
        fallback_kernel<<<NB * NV, 64, 0, stream>>>(neigh, x, W, bias, out);
    }
}